// Round 4
// baseline (139.615 us; speedup 1.0000x reference)
//
#include <hip/hip_runtime.h>
#include <hip/hip_bf16.h>

// Problem dims (fixed): B=2, N=1024, SR=1, S=seq_in*nh_in=64, NV=4, NC=32,
// NLON=NLAT=4 -> NJ=16 basis pairs. NWIN = B*N = 2048.
#define NWIN 2048
#define SDIM 64
#define NJ 16

__device__ __forceinline__ float bf2f(unsigned int u16) {
    union { unsigned int i; float f; } v;
    v.i = u16 << 16;
    return v.f;
}

// One window per wave. Phase 1: lane = s computes Gaussian weights -> LDS,
// wave-reduces the normalizer S[j] (folded to epilogue as 1/S).
// Phase 2: half-wave = s-row parity, lane = (v, c4) holding 4 channels;
// 32 iterations of 16B-coalesced x loads (f32) / 8B (bf16) against
// LDS-broadcast weights; cross-half shfl reduction; 16B stores.
//
// Dtypes (established R1-R3): params + output f32; x/coords probe-detected
// per buffer (bf16 N(0,1) exp field in [102,134] at even u16 idx vs f32
// mantissa junk; 16-word vote).
__global__ __launch_bounds__(256, 2) void gauss_agg_kernel(
    const void* __restrict__ x,       // (NWIN, S, NV=4, NC=32)
    const void* __restrict__ clon,    // (NWIN, S)
    const void* __restrict__ clat,    // (NWIN, S)
    const void* __restrict__ mlon,    // (4)
    const void* __restrict__ mlat,    // (4)
    const void* __restrict__ sigma,   // (1)
    float* __restrict__ out)          // (NWIN, NV, NJ, NC) f32
{
    __shared__ alignas(16) float s_wlon[4][SDIM][4];
    __shared__ alignas(16) float s_wlat[4][SDIM][4];
    __shared__ float s_sinv[4][NJ];
    __shared__ int s_flags;

    const int tid  = threadIdx.x;
    const int w4   = tid >> 6;     // window slot within block
    const int lane = tid & 63;
    const int win  = blockIdx.x * 4 + w4;

    // ---------------- dtype probes (uniform) ----------------
    if (tid == 0) {
        const unsigned short* px = (const unsigned short*)x;
        const unsigned short* pc = (const unsigned short*)clon;
        int vx = 0, vc = 0;
#pragma unroll
        for (int i = 0; i < 16; ++i) {
            const int ex = (px[2 * i] >> 7) & 0xFF;
            vx += (ex >= 102 && ex <= 134);
            const int ec = (pc[2 * i] >> 7) & 0xFF;
            vc += (ec >= 102 && ec <= 134);
        }
        int f = 0;
        if (vx >= 12) f |= 1;                                   // x is bf16
        if (vc >= 12) f |= 2;                                   // coords bf16
        if (((const unsigned short*)mlon)[0] != 0) f |= 4;      // mus bf16
        if (((const unsigned short*)sigma)[0] != 0) f |= 8;     // sigma bf16
        s_flags = f;
    }
    __syncthreads();
    const int flags = s_flags;
    const bool xb = flags & 1, cb = flags & 2, mb = flags & 4, sb = flags & 8;

    // ---------------- phase 1: weights (lane == s) ----------------
    const float sigraw = sb ? bf2f(((const unsigned short*)sigma)[0])
                            : ((const float*)sigma)[0];
    const float inv = 1.0f / fmaxf(sigraw, 1e-10f);

    float mlo[4], mla[4];
#pragma unroll
    for (int l = 0; l < 4; ++l) {
        mlo[l] = mb ? bf2f(((const unsigned short*)mlon)[l])
                    : ((const float*)mlon)[l];
        mla[l] = mb ? bf2f(((const unsigned short*)mlat)[l])
                    : ((const float*)mlat)[l];
    }

    float lon, lat;
    if (cb) {
        lon = bf2f(((const unsigned short*)clon)[win * SDIM + lane]);
        lat = bf2f(((const unsigned short*)clat)[win * SDIM + lane]);
    } else {
        lon = ((const float*)clon)[win * SDIM + lane];
        lat = ((const float*)clat)[win * SDIM + lane];
    }

    float wlon[4], wlat[4];
#pragma unroll
    for (int l = 0; l < 4; ++l) {
        const float dlo = (lon - mlo[l]) * inv;
        wlon[l] = __expf(-0.5f * dlo * dlo);
        const float dla = (lat - mla[l]) * inv;
        wlat[l] = __expf(-0.5f * dla * dla);
    }
    *reinterpret_cast<float4*>(&s_wlon[w4][lane][0]) =
        make_float4(wlon[0], wlon[1], wlon[2], wlon[3]);
    *reinterpret_cast<float4*>(&s_wlat[w4][lane][0]) =
        make_float4(wlat[0], wlat[1], wlat[2], wlat[3]);

    // normalizer S[j] via wave butterfly (whole 64-lane wave = one window)
    float p[NJ];
#pragma unroll
    for (int lo = 0; lo < 4; ++lo)
#pragma unroll
        for (int la = 0; la < 4; ++la)
            p[lo * 4 + la] = wlon[lo] * wlat[la];
#pragma unroll
    for (int j = 0; j < NJ; ++j) {
        float v = p[j];
#pragma unroll
        for (int off = 1; off < 64; off <<= 1)
            v += __shfl_xor(v, off, 64);
        p[j] = v;
    }
    if (lane == 0) {
#pragma unroll
        for (int j = 0; j < NJ; ++j)
            s_sinv[w4][j] = 1.0f / p[j];
    }
    __syncthreads();

    // ---------------- phase 2: aggregation ----------------
    // half-wave = s-row parity; within half: v = variable, c4 = 4-channel grp
    const int half = lane >> 5;         // 0/1
    const int l5   = lane & 31;
    const int v    = l5 >> 3;           // 0..3
    const int c4   = l5 & 7;            // channels c = 4*c4 .. 4*c4+3

    const float4* wl4 = reinterpret_cast<const float4*>(&s_wlon[w4][0][0]);
    const float4* wt4 = reinterpret_cast<const float4*>(&s_wlat[w4][0][0]);

    float acc[NJ][4];
#pragma unroll
    for (int j = 0; j < NJ; ++j)
#pragma unroll
        for (int k = 0; k < 4; ++k) acc[j][k] = 0.0f;

    if (xb) {
        // bf16: uint2 = 4 bf16 = 4 channels. row = 32 uint2; win = 2048 uint2
        const uint2* xp = (const uint2*)x +
                          ((size_t)win * 2048 + v * 8 + c4);
#pragma unroll 4
        for (int s = 0; s < 32; ++s) {
            const int s2 = 2 * s + half;
            const uint2 u = xp[s2 * 32];
            union { unsigned int i; float fl; } a0, a1, a2, a3;
            a0.i = u.x << 16; a1.i = u.x & 0xffff0000u;
            a2.i = u.y << 16; a3.i = u.y & 0xffff0000u;
            const float f[4] = { a0.fl, a1.fl, a2.fl, a3.fl };
            const float4 wl = wl4[s2];
            const float4 wt = wt4[s2];
            const float wlv[4] = { wl.x, wl.y, wl.z, wl.w };
            const float wtv[4] = { wt.x, wt.y, wt.z, wt.w };
            float t[4][4];
#pragma unroll
            for (int la = 0; la < 4; ++la)
#pragma unroll
                for (int k = 0; k < 4; ++k) t[la][k] = f[k] * wtv[la];
#pragma unroll
            for (int lo = 0; lo < 4; ++lo)
#pragma unroll
                for (int la = 0; la < 4; ++la)
#pragma unroll
                    for (int k = 0; k < 4; ++k)
                        acc[lo * 4 + la][k] += wlv[lo] * t[la][k];
        }
    } else {
        // f32: float4 = 4 channels. row = 32 float4; win = 2048 float4
        const float4* xp = (const float4*)x +
                           ((size_t)win * 2048 + v * 8 + c4);
#pragma unroll 4
        for (int s = 0; s < 32; ++s) {
            const int s2 = 2 * s + half;
            const float4 xv = xp[s2 * 32];
            const float f[4] = { xv.x, xv.y, xv.z, xv.w };
            const float4 wl = wl4[s2];
            const float4 wt = wt4[s2];
            const float wlv[4] = { wl.x, wl.y, wl.z, wl.w };
            const float wtv[4] = { wt.x, wt.y, wt.z, wt.w };
            float t[4][4];
#pragma unroll
            for (int la = 0; la < 4; ++la)
#pragma unroll
                for (int k = 0; k < 4; ++k) t[la][k] = f[k] * wtv[la];
#pragma unroll
            for (int lo = 0; lo < 4; ++lo)
#pragma unroll
                for (int la = 0; la < 4; ++la)
#pragma unroll
                    for (int k = 0; k < 4; ++k)
                        acc[lo * 4 + la][k] += wlv[lo] * t[la][k];
        }
    }

    // cross-half reduction (halves hold disjoint s-subsets)
#pragma unroll
    for (int j = 0; j < NJ; ++j)
#pragma unroll
        for (int k = 0; k < 4; ++k)
            acc[j][k] += __shfl_xor(acc[j][k], 32, 64);

    // ---------------- epilogue: normalize, store f32 ----------------
    // half 0 stores j = 0..7, half 1 stores j = 8..15
    float4* op = reinterpret_cast<float4*>(out);
    const int jbase = half * 8;
#pragma unroll
    for (int j2 = 0; j2 < 8; ++j2) {
        const int j = jbase + j2;
        const float si = s_sinv[w4][j];
        // out float4 index = ((win*4 + v)*16 + j)*8 + c4
        op[((size_t)(win * 4 + v) * NJ + j) * 8 + c4] =
            make_float4(acc[j][0] * si, acc[j][1] * si,
                        acc[j][2] * si, acc[j][3] * si);
    }
}

extern "C" void kernel_launch(void* const* d_in, const int* in_sizes, int n_in,
                              void* d_out, int out_size, void* d_ws, size_t ws_size,
                              hipStream_t stream) {
    dim3 grid(NWIN / 4);   // 512 blocks, 4 windows (waves) each
    dim3 block(256);
    gauss_agg_kernel<<<grid, block, 0, stream>>>(
        d_in[0], d_in[1], d_in[2], d_in[3], d_in[4], d_in[5],
        (float*)d_out);
}

// Round 5
// 122.637 us; speedup vs baseline: 1.1384x; 1.1384x over previous
//
#include <hip/hip_runtime.h>
#include <hip/hip_bf16.h>

// Problem dims (fixed): B=2, N=1024, SR=1, S=seq_in*nh_in=64, NV=4, NC=32,
// NLON=NLAT=4 -> NJ=16 basis pairs. NWIN = B*N = 2048.
#define NWIN 2048
#define SDIM 64
#define NJ 16

__device__ __forceinline__ float bf2f(unsigned int u16) {
    union { unsigned int i; float f; } v;
    v.i = u16 << 16;
    return v.f;
}

// R5 structure: one window per BLOCK, one (window, v) per WAVE.
//   grid 2048 x 256  ->  8 blocks/CU candidate occupancy (R4 had 2).
//   lane = (sp = lane>>4: s-phase 0..3, c2 = lane&15: channel pair).
//   Each lane: 16 independent 4B x-loads (s = 4*it+sp), acc[16][2] = 32 VGPRs
//   (R4's acc[16][4]=64 spilled to scratch: VGPR_Count=64 + WRITE_SIZE 5x
//   ideal = smoking gun). Cross-phase shfl_xor(16,32) reduction; j split
//   across phases for stores. Normalizer folded to epilogue as 1/S[j].
//
// Dtypes (R1-R4 evidence): x bf16 (FETCH~35MB), coords f32, params f32,
// out f32. Probes retained (deterministic for params, 16-word exponent vote
// for x/coords) so a dtype flip cannot break correctness.
__global__ __launch_bounds__(256, 4) void gauss_agg_kernel(
    const void* __restrict__ x,       // (NWIN, S, NV=4, NC=32)
    const void* __restrict__ clon,    // (NWIN, S)
    const void* __restrict__ clat,    // (NWIN, S)
    const void* __restrict__ mlon,    // (4)
    const void* __restrict__ mlat,    // (4)
    const void* __restrict__ sigma,   // (1)
    float* __restrict__ out)          // (NWIN, NV, NJ, NC) f32
{
    __shared__ alignas(16) float s_wlon[SDIM][4];
    __shared__ alignas(16) float s_wlat[SDIM][4];
    __shared__ float s_sinv[NJ];
    __shared__ int s_flags;

    const int tid = threadIdx.x;
    const int win = blockIdx.x;

    // ---------------- dtype probes (uniform) ----------------
    if (tid == 0) {
        const unsigned short* px = (const unsigned short*)x;
        const unsigned short* pc = (const unsigned short*)clon;
        int vx = 0, vc = 0;
#pragma unroll
        for (int i = 0; i < 16; ++i) {
            const int ex = (px[2 * i] >> 7) & 0xFF;
            vx += (ex >= 102 && ex <= 134);
            const int ec = (pc[2 * i] >> 7) & 0xFF;
            vc += (ec >= 102 && ec <= 134);
        }
        int f = 0;
        if (vx >= 12) f |= 1;                                   // x is bf16
        if (vc >= 12) f |= 2;                                   // coords bf16
        if (((const unsigned short*)mlon)[0] != 0) f |= 4;      // mus bf16
        if (((const unsigned short*)sigma)[0] != 0) f |= 8;     // sigma bf16
        s_flags = f;
    }
    __syncthreads();
    const int flags = s_flags;
    const bool xb = flags & 1, cb = flags & 2, mb = flags & 4, sb = flags & 8;

    // ---------------- phase 1: weights (wave 0, lane == s) ----------------
    if (tid < 64) {
        const int lane = tid;
        const float sigraw = sb ? bf2f(((const unsigned short*)sigma)[0])
                                : ((const float*)sigma)[0];
        const float inv = 1.0f / fmaxf(sigraw, 1e-10f);

        float mlo[4], mla[4];
#pragma unroll
        for (int l = 0; l < 4; ++l) {
            mlo[l] = mb ? bf2f(((const unsigned short*)mlon)[l])
                        : ((const float*)mlon)[l];
            mla[l] = mb ? bf2f(((const unsigned short*)mlat)[l])
                        : ((const float*)mlat)[l];
        }

        float lon, lat;
        if (cb) {
            lon = bf2f(((const unsigned short*)clon)[win * SDIM + lane]);
            lat = bf2f(((const unsigned short*)clat)[win * SDIM + lane]);
        } else {
            lon = ((const float*)clon)[win * SDIM + lane];
            lat = ((const float*)clat)[win * SDIM + lane];
        }

        float wlon[4], wlat[4];
#pragma unroll
        for (int l = 0; l < 4; ++l) {
            const float dlo = (lon - mlo[l]) * inv;
            wlon[l] = __expf(-0.5f * dlo * dlo);
            const float dla = (lat - mla[l]) * inv;
            wlat[l] = __expf(-0.5f * dla * dla);
        }
        *reinterpret_cast<float4*>(&s_wlon[lane][0]) =
            make_float4(wlon[0], wlon[1], wlon[2], wlon[3]);
        *reinterpret_cast<float4*>(&s_wlat[lane][0]) =
            make_float4(wlat[0], wlat[1], wlat[2], wlat[3]);

        // normalizer S[j] via wave butterfly over s
        float p[NJ];
#pragma unroll
        for (int lo = 0; lo < 4; ++lo)
#pragma unroll
            for (int la = 0; la < 4; ++la)
                p[lo * 4 + la] = wlon[lo] * wlat[la];
#pragma unroll
        for (int j = 0; j < NJ; ++j) {
            float v = p[j];
#pragma unroll
            for (int off = 1; off < 64; off <<= 1)
                v += __shfl_xor(v, off, 64);
            p[j] = v;
        }
        if (lane == 0) {
#pragma unroll
            for (int j = 0; j < NJ; ++j)
                s_sinv[j] = 1.0f / p[j];
        }
    }
    __syncthreads();

    // ---------------- phase 2: aggregation (wave = v) ----------------
    const int v    = tid >> 6;      // variable 0..3 (one per wave)
    const int lane = tid & 63;
    const int sp   = lane >> 4;     // s-phase 0..3: s = 4*it + sp
    const int c2   = lane & 15;     // channel pair (c = 2*c2, 2*c2+1)

    const float4* wl4 = reinterpret_cast<const float4*>(&s_wlon[0][0]);
    const float4* wt4 = reinterpret_cast<const float4*>(&s_wlat[0][0]);

    float acc[NJ][2];
#pragma unroll
    for (int j = 0; j < NJ; ++j) { acc[j][0] = 0.0f; acc[j][1] = 0.0f; }

    // flat index of (win, s, v, c2) in 2-element units: win*4096 + s*64 + v*16 + c2
    const size_t base = (size_t)win * 4096 + v * 16 + c2;

    if (xb) {
        const unsigned int* xp = (const unsigned int*)x + base;
#pragma unroll 8
        for (int it = 0; it < 16; ++it) {
            const int s = 4 * it + sp;
            const unsigned int u = xp[s * 64];
            union { unsigned int i; float fl; } u0, u1;
            u0.i = u << 16;
            u1.i = u & 0xffff0000u;
            const float f0 = u0.fl, f1 = u1.fl;
            const float4 wl = wl4[s];
            const float4 wt = wt4[s];
            const float wlv[4] = { wl.x, wl.y, wl.z, wl.w };
            const float wtv[4] = { wt.x, wt.y, wt.z, wt.w };
            float t0[4], t1[4];
#pragma unroll
            for (int la = 0; la < 4; ++la) { t0[la] = f0 * wtv[la]; t1[la] = f1 * wtv[la]; }
#pragma unroll
            for (int lo = 0; lo < 4; ++lo)
#pragma unroll
                for (int la = 0; la < 4; ++la) {
                    acc[lo * 4 + la][0] += wlv[lo] * t0[la];
                    acc[lo * 4 + la][1] += wlv[lo] * t1[la];
                }
        }
    } else {
        const float2* xp = (const float2*)x + base;
#pragma unroll 8
        for (int it = 0; it < 16; ++it) {
            const int s = 4 * it + sp;
            const float2 xv = xp[s * 64];
            const float f0 = xv.x, f1 = xv.y;
            const float4 wl = wl4[s];
            const float4 wt = wt4[s];
            const float wlv[4] = { wl.x, wl.y, wl.z, wl.w };
            const float wtv[4] = { wt.x, wt.y, wt.z, wt.w };
            float t0[4], t1[4];
#pragma unroll
            for (int la = 0; la < 4; ++la) { t0[la] = f0 * wtv[la]; t1[la] = f1 * wtv[la]; }
#pragma unroll
            for (int lo = 0; lo < 4; ++lo)
#pragma unroll
                for (int la = 0; la < 4; ++la) {
                    acc[lo * 4 + la][0] += wlv[lo] * t0[la];
                    acc[lo * 4 + la][1] += wlv[lo] * t1[la];
                }
        }
    }

    // cross-phase reduction over sp (lane bits 4 and 5)
#pragma unroll
    for (int j = 0; j < NJ; ++j)
#pragma unroll
        for (int k = 0; k < 2; ++k) {
            acc[j][k] += __shfl_xor(acc[j][k], 16, 64);
            acc[j][k] += __shfl_xor(acc[j][k], 32, 64);
        }

    // ---------------- epilogue: normalize, store f32 ----------------
    // phase group sp stores j = sp*4 .. sp*4+3 (all groups hold full sums)
    float2* op = reinterpret_cast<float2*>(out);
#pragma unroll
    for (int jj = 0; jj < 4; ++jj) {
        const int j = sp * 4 + jj;
        const float si = s_sinv[j];
        // out float2 index = ((win*4 + v)*16 + j)*16 + c2
        op[((size_t)(win * 4 + v) * NJ + j) * 16 + c2] =
            make_float2(acc[j][0] * si, acc[j][1] * si);
    }
}

extern "C" void kernel_launch(void* const* d_in, const int* in_sizes, int n_in,
                              void* d_out, int out_size, void* d_ws, size_t ws_size,
                              hipStream_t stream) {
    dim3 grid(NWIN);       // one window per block, 4 v-waves per block
    dim3 block(256);
    gauss_agg_kernel<<<grid, block, 0, stream>>>(
        d_in[0], d_in[1], d_in[2], d_in[3], d_in[4], d_in[5],
        (float*)d_out);
}